// Round 16
// baseline (142.457 us; speedup 1.0000x reference)
//
#include <hip/hip_runtime.h>
#include <math.h>

namespace {

constexpr int H = 1024;
constexpr int W = 1024;
constexpr int HW = H * W;
constexpr int TILE = 64;             // output tile edge
constexpr int HALO = 16;             // = steps fused per launch
constexpr int P = 96;                // halo'd tile edge
constexpr int NLAUNCH = 4;           // 4 x 16 = 64 steps
constexpr int NTX = W / TILE;        // 16 tiles per dim
constexpr int NTHREADS = 1024;       // 16 waves = 4/SIMD
constexpr int PITCHF = P + 4;        // 100 floats/row: b128-aligned rows; pad
                                     // legalizes the +4 right-edge read.

typedef float f2 __attribute__((ext_vector_type(2)));
typedef float f4 __attribute__((ext_vector_type(4)));

__device__ __forceinline__ float clampf(float v, float lo, float hi) {
    return fminf(fmaxf(v, lo), hi);           // -> v_med3_f32
}
// Packed 2xfp32 VOP3P ops (CDNA gfx90a+; default op_sel = natural packed
// semantics). f2 = 64-bit VGPR pair under the "v" constraint.
__device__ __forceinline__ f2 pk_fma(f2 a, f2 b, f2 c) {
    f2 d;
    asm("v_pk_fma_f32 %0, %1, %2, %3" : "=v"(d) : "v"(a), "v"(b), "v"(c));
    return d;
}
__device__ __forceinline__ f2 pk_add(f2 a, f2 b) {
    f2 d;
    asm("v_pk_add_f32 %0, %1, %2" : "=v"(d) : "v"(a), "v"(b));
    return d;
}
__device__ __forceinline__ f2 pk_mul(f2 a, f2 b) {
    f2 d;
    asm("v_pk_mul_f32 %0, %1, %2" : "=v"(d) : "v"(a), "v"(b));
    return d;
}
__device__ __forceinline__ f2 clamp2(f2 v, float lo, float hi) {
    f2 r;
    r.x = clampf(v.x, lo, hi);                // 2x v_med3_f32 (no packed med3)
    r.y = clampf(v.y, lo, hi);
    return r;
}
__device__ __forceinline__ f2 lo2(f4 q) { return __builtin_shufflevector(q, q, 0, 1); }
__device__ __forceinline__ f2 hi2(f4 q) { return __builtin_shufflevector(q, q, 2, 3); }
__device__ __forceinline__ f4 ld4f(const float* p) {
    return *reinterpret_cast<const f4*>(p);
}
// DPP wave shifts (correctness validated R12-R15): 0x138 -> value from lane-1
// (left neighbor); 0x130 -> value from lane+1 (right neighbor).
// bound_ctrl=false: boundary lanes keep their own value.
__device__ __forceinline__ float dpp_left(float x) {
    int r = __builtin_amdgcn_update_dpp(__float_as_int(x), __float_as_int(x),
                                        0x138, 0xF, 0xF, false);
    return __int_as_float(r);
}
__device__ __forceinline__ float dpp_right(float x) {
    int r = __builtin_amdgcn_update_dpp(__float_as_int(x), __float_as_int(x),
                                        0x130, 0xF, 0xF, false);
    return __int_as_float(r);
}

struct Consts {        // broadcast constant pairs (held in VGPR pairs)
    f2 inv2, neg4, neg1, fpair, negf, Du2, Dv2, fkneg, dt2;
};

// One Gray-Scott step for a 4-px row segment, both fields, forced-packed.
// Merged 5-point laplacian (DX2 == DY2 exactly on this grid).
__device__ __forceinline__ void row_step(
    f4 uN, f4 uC, f4 uD, float uL, float uR,
    f4 vN, f4 vC, f4 vD, float vL, float vR,
    const Consts& c, f4* outU, f4* outV)
{
    const f2 a0u = lo2(uC), a1u = hi2(uC);
    const f2 a0v = lo2(vC), a1v = hi2(vC);

    const f2 l0u = { uL, a0u.x };
    const f2 mmu = { a0u.y, a1u.x };
    const f2 r1u = { a1u.y, uR };
    const f2 l0v = { vL, a0v.x };
    const f2 mmv = { a0v.y, a1v.x };
    const f2 r1v = { a1v.y, vR };

    // lap = (left+right + up+down - 4*c) * inv2, clamped to [-10,10]
    const f2 s0u = pk_add(pk_add(l0u, mmu), pk_add(lo2(uN), lo2(uD)));
    const f2 s1u = pk_add(pk_add(mmu, r1u), pk_add(hi2(uN), hi2(uD)));
    const f2 s0v = pk_add(pk_add(l0v, mmv), pk_add(lo2(vN), lo2(vD)));
    const f2 s1v = pk_add(pk_add(mmv, r1v), pk_add(hi2(vN), hi2(vD)));
    const f2 lu0 = clamp2(pk_mul(pk_fma(a0u, c.neg4, s0u), c.inv2), -10.0f, 10.0f);
    const f2 lu1 = clamp2(pk_mul(pk_fma(a1u, c.neg4, s1u), c.inv2), -10.0f, 10.0f);
    const f2 lv0 = clamp2(pk_mul(pk_fma(a0v, c.neg4, s0v), c.inv2), -10.0f, 10.0f);
    const f2 lv1 = clamp2(pk_mul(pk_fma(a1v, c.neg4, s1v), c.inv2), -10.0f, 10.0f);

    const f2 uvv0 = pk_mul(pk_mul(a0u, a0v), a0v);
    const f2 uvv1 = pk_mul(pk_mul(a1u, a1v), a1v);

    // du = Du*lu - uvv + f*(1-u);  dv = Dv*lv + uvv - fk*v
    const f2 tu0 = pk_fma(uvv0, c.neg1, pk_fma(a0u, c.negf, c.fpair));
    const f2 tu1 = pk_fma(uvv1, c.neg1, pk_fma(a1u, c.negf, c.fpair));
    const f2 tv0 = pk_fma(a0v, c.fkneg, uvv0);
    const f2 tv1 = pk_fma(a1v, c.fkneg, uvv1);
    const f2 du0 = clamp2(pk_fma(c.Du2, lu0, tu0), -1.0f, 1.0f);
    const f2 du1 = clamp2(pk_fma(c.Du2, lu1, tu1), -1.0f, 1.0f);
    const f2 dv0 = clamp2(pk_fma(c.Dv2, lv0, tv0), -1.0f, 1.0f);
    const f2 dv1 = clamp2(pk_fma(c.Dv2, lv1, tv1), -1.0f, 1.0f);

    const f2 ou0 = clamp2(pk_fma(du0, c.dt2, a0u), 0.0f, 2.0f);
    const f2 ou1 = clamp2(pk_fma(du1, c.dt2, a1u), 0.0f, 2.0f);
    const f2 ov0 = clamp2(pk_fma(dv0, c.dt2, a0v), 0.0f, 2.0f);
    const f2 ov1 = clamp2(pk_fma(dv1, c.dt2, a1v), 0.0f, 2.0f);

    *outU = __builtin_shufflevector(ou0, ou1, 0, 1, 2, 3);
    *outV = __builtin_shufflevector(ov0, ov1, 0, 1, 2, 3);
}

// 16 fused Gray-Scott steps on a 64x64 tile, halo 16 (R15 structure: DPP
// edges + sparse b32 fallbacks, fused step-16 global store). NEW: inner math
// forced to VOP3P packed fp32 via inline asm + merged laplacian (DX2==DY2).
// Step s computes rows/cols [s,95-s]; outside is clamped-finite garbage
// never read by the valid region.
__global__ __launch_bounds__(NTHREADS) void gs_tile(
    const float* __restrict__ Uin, const float* __restrict__ Vin,
    float* __restrict__ Uout, float* __restrict__ Vout,
    const float* __restrict__ pLogDu, const float* __restrict__ pLogDv,
    const float* __restrict__ pf, const float* __restrict__ pk,
    float inv2, float dt)
{
    __shared__ __align__(16) float sU[2][P * PITCHF];   // 2 x 38.4 KB
    __shared__ __align__(16) float sV[2][P * PITCHF];   // total 153.6 KB

    const int tid  = threadIdx.x;
    const int lane = tid & 63;
    const int bx = blockIdx.x & (NTX - 1);
    const int by = blockIdx.x >> 4;
    const int gx0 = bx * TILE - HALO;
    const int gy0 = by * TILE - HALO;

    const float Du = clampf(expf(pLogDu[0]), 0.001f, 1.0f);
    const float Dv = clampf(expf(pLogDv[0]), 0.001f, 1.0f);
    const float f = pf[0], k = pk[0];
    const float fk = f + k;
    Consts cst;
    cst.inv2  = f2{ inv2, inv2 };
    cst.neg4  = f2{ -4.0f, -4.0f };
    cst.neg1  = f2{ -1.0f, -1.0f };
    cst.fpair = f2{ f, f };
    cst.negf  = f2{ -f, -f };
    cst.Du2   = f2{ Du, Du };
    cst.Dv2   = f2{ Dv, Dv };
    cst.fkneg = f2{ -fk, -fk };
    cst.dt2   = f2{ dt, dt };

    // ---- load 96x96 halo'd tile (periodic wrap). No clamps: inputs are in
    // [0,2] by construction, so the reference's leading clip is the identity.
    for (int t = tid; t < P * (P / 4); t += NTHREADS) {   // 2304 4-px strips
        const int r  = t / (P / 4);
        const int c4 = (t - r * (P / 4)) * 4;
        const int gy = (gy0 + r) & (H - 1);
        const int gx = (gx0 + c4) & (W - 1);              // 4-aligned, no mid-vec wrap
        *reinterpret_cast<f4*>(&sU[0][r * PITCHF + c4]) = ld4f(Uin + gy * W + gx);
        *reinterpret_cast<f4*>(&sV[0][r * PITCHF + c4]) = ld4f(Vin + gy * W + gx);
    }
    __syncthreads();

    int b = 0;

#define GS_STEP(S, NC, C4LO)                                                     \
    {                                                                            \
        const float* __restrict__ cU = sU[b];                                    \
        const float* __restrict__ cV = sV[b];                                    \
        float* __restrict__ nU = sU[b ^ 1];                                      \
        float* __restrict__ nV = sV[b ^ 1];                                      \
        const int npair = (P - 2 * (S)) >> 1;                                    \
        const int tasks = npair * (NC);                                          \
        for (int t = tid; t < tasks; t += NTHREADS) {                            \
            const int pr  = t / (NC);                                            \
            const int j   = t - pr * (NC);                                       \
            const int row = (S) + 2 * pr;                                        \
            const int c4  = (C4LO) + j * 4;                                      \
            const int oA  = row * PITCHF + c4;                                   \
            const f4 uN = ld4f(cU + oA - PITCHF);                                \
            const f4 uA = ld4f(cU + oA);                                         \
            const f4 uB = ld4f(cU + oA + PITCHF);                                \
            const f4 uS = ld4f(cU + oA + 2 * PITCHF);                            \
            const f4 vN = ld4f(cV + oA - PITCHF);                                \
            const f4 vA = ld4f(cV + oA);                                         \
            const f4 vB = ld4f(cV + oA + PITCHF);                                \
            const f4 vS = ld4f(cV + oA + 2 * PITCHF);                            \
            float uLa = dpp_left(uA.w), uRa = dpp_right(uA.x);                   \
            float uLb = dpp_left(uB.w), uRb = dpp_right(uB.x);                   \
            float vLa = dpp_left(vA.w), vRa = dpp_right(vA.x);                   \
            float vLb = dpp_left(vB.w), vRb = dpp_right(vB.x);                   \
            if ((lane == 0 || j == 0) && c4 > 0) {                               \
                uLa = cU[oA - 1]; uLb = cU[oA + PITCHF - 1];                     \
                vLa = cV[oA - 1]; vLb = cV[oA + PITCHF - 1];                     \
            }                                                                    \
            if (lane == 63 || j == (NC) - 1) {                                   \
                uRa = cU[oA + 4]; uRb = cU[oA + PITCHF + 4];                     \
                vRa = cV[oA + 4]; vRb = cV[oA + PITCHF + 4];                     \
            }                                                                    \
            f4 ouA, ovA, ouB, ovB;                                               \
            row_step(uN, uA, uB, uLa, uRa, vN, vA, vB, vLa, vRa,                 \
                     cst, &ouA, &ovA);                                           \
            row_step(uA, uB, uS, uLb, uRb, vA, vB, vS, vLb, vRb,                 \
                     cst, &ouB, &ovB);                                           \
            *reinterpret_cast<f4*>(nU + oA)          = ouA;                      \
            *reinterpret_cast<f4*>(nU + oA + PITCHF) = ouB;                      \
            *reinterpret_cast<f4*>(nV + oA)          = ovA;                      \
            *reinterpret_cast<f4*>(nV + oA + PITCHF) = ovB;                      \
        }                                                                        \
        b ^= 1;                                                                  \
        __syncthreads();                                                         \
    }

    for (int s = 1; s <= 3; ++s)   GS_STEP(s, 24,  0);    // s=1..3
    for (int s = 4; s <= 7; ++s)   GS_STEP(s, 22,  4);    // s=4..7
    for (int s = 8; s <= 11; ++s)  GS_STEP(s, 20,  8);    // s=8..11
    for (int s = 12; s <= 15; ++s) GS_STEP(s, 18, 12);    // s=12..15

    // ---- step 16: region is exactly the interior [16,79]^2 -> write global.
    // NC=16 divides 64: j==0 covers lane 0, j==15 covers lane 63.
    {
        const float* __restrict__ cU = sU[b];
        const float* __restrict__ cV = sV[b];
        if (tid < 32 * 16) {                              // 512 tasks
            const int pr  = tid / 16;
            const int j   = tid - pr * 16;
            const int row = 16 + 2 * pr;
            const int c4  = 16 + j * 4;
            const int oA  = row * PITCHF + c4;
            const f4 uN = ld4f(cU + oA - PITCHF);
            const f4 uA = ld4f(cU + oA);
            const f4 uB = ld4f(cU + oA + PITCHF);
            const f4 uS = ld4f(cU + oA + 2 * PITCHF);
            const f4 vN = ld4f(cV + oA - PITCHF);
            const f4 vA = ld4f(cV + oA);
            const f4 vB = ld4f(cV + oA + PITCHF);
            const f4 vS = ld4f(cV + oA + 2 * PITCHF);
            float uLa = dpp_left(uA.w), uRa = dpp_right(uA.x);
            float uLb = dpp_left(uB.w), uRb = dpp_right(uB.x);
            float vLa = dpp_left(vA.w), vRa = dpp_right(vA.x);
            float vLb = dpp_left(vB.w), vRb = dpp_right(vB.x);
            if (j == 0) {
                uLa = cU[oA - 1]; uLb = cU[oA + PITCHF - 1];
                vLa = cV[oA - 1]; vLb = cV[oA + PITCHF - 1];
            }
            if (j == 15) {
                uRa = cU[oA + 4]; uRb = cU[oA + PITCHF + 4];
                vRa = cV[oA + 4]; vRb = cV[oA + PITCHF + 4];
            }
            f4 ouA, ovA, ouB, ovB;
            row_step(uN, uA, uB, uLa, uRa, vN, vA, vB, vLa, vRa,
                     cst, &ouA, &ovA);
            row_step(uA, uB, uS, uLb, uRb, vA, vB, vS, vLb, vRb,
                     cst, &ouB, &ovB);
            const int go = (by * TILE + row - HALO) * W + bx * TILE + (c4 - HALO);
            *reinterpret_cast<f4*>(Uout + go)     = ouA;
            *reinterpret_cast<f4*>(Uout + go + W) = ouB;
            *reinterpret_cast<f4*>(Vout + go)     = ovA;
            *reinterpret_cast<f4*>(Vout + go + W) = ovB;
        }
    }
#undef GS_STEP
}

} // namespace

extern "C" void kernel_launch(void* const* d_in, const int* in_sizes, int n_in,
                              void* d_out, int out_size, void* d_ws, size_t ws_size,
                              hipStream_t stream) {
    const float* U0     = (const float*)d_in[0];
    const float* V0     = (const float*)d_in[1];
    const float* pLogDu = (const float*)d_in[2];
    const float* pLogDv = (const float*)d_in[3];
    const float* pf     = (const float*)d_in[4];
    const float* pk     = (const float*)d_in[5];
    // d_in[6] = steps (int32) — fixed at 64 by the problem definition.

    float* wsU  = (float*)d_ws;   // 4 MB
    float* wsV  = wsU + HW;       // 4 MB
    float* outU = (float*)d_out;  // output layout: [U (HW) | V (HW)]
    float* outV = outU + HW;

    const double dx  = 1.0 / (W - 1);
    const double dx2 = dx * dx;                 // == dy2 exactly (square grid)
    const float inv2 = (float)(1.0 / dx2);
    const float dtf  = (float)(0.1 * dx2 / (4.0 * 0.16));

    const int grid = (H / TILE) * (W / TILE);   // 256 blocks = 1 per CU

    // 4 launches of 16 fused steps, ping-pong ws <-> d_out; launch 3 (odd)
    // leaves the final state exactly in d_out.
    const float* cu = U0;
    const float* cv = V0;
    for (int l = 0; l < NLAUNCH; ++l) {
        float* nu;
        float* nv;
        if (l & 1) { nu = outU; nv = outV; }
        else       { nu = wsU;  nv = wsV;  }
        gs_tile<<<grid, NTHREADS, 0, stream>>>(cu, cv, nu, nv,
                                               pLogDu, pLogDv, pf, pk,
                                               inv2, dtf);
        cu = nu; cv = nv;
    }
}

// Round 17
// 119.590 us; speedup vs baseline: 1.1912x; 1.1912x over previous
//
#include <hip/hip_runtime.h>
#include <math.h>

namespace {

constexpr int H = 1024;
constexpr int W = 1024;
constexpr int HW = H * W;
constexpr int TILE = 64;             // output tile edge
constexpr int HALO = 16;             // = steps fused per launch
constexpr int P = 96;                // halo'd tile edge
constexpr int NLAUNCH = 4;           // 4 x 16 = 64 steps
constexpr int NTX = W / TILE;        // 16 tiles per dim
constexpr int NTHREADS = 1024;       // 16 waves = 4/SIMD
constexpr int PITCHF = P + 4;        // 100 floats/row: b128-aligned rows; pad
                                     // legalizes the +4 right-edge read.

typedef float f2 __attribute__((ext_vector_type(2)));
typedef float f4 __attribute__((ext_vector_type(4)));

__device__ __forceinline__ float clampf(float v, float lo, float hi) {
    return fminf(fmaxf(v, lo), hi);           // -> v_med3_f32
}
__device__ __forceinline__ f2 clamp2(f2 v, float lo, float hi) {
    f2 r;
    r.x = fminf(fmaxf(v.x, lo), hi);
    r.y = fminf(fmaxf(v.y, lo), hi);
    return r;
}
__device__ __forceinline__ f2 lo2(f4 q) { return __builtin_shufflevector(q, q, 0, 1); }
__device__ __forceinline__ f2 hi2(f4 q) { return __builtin_shufflevector(q, q, 2, 3); }
__device__ __forceinline__ f4 ld4f(const float* p) {
    return *reinterpret_cast<const f4*>(p);
}
// DPP wave shifts (correctness validated R12-R16): 0x138 -> value from lane-1
// (left neighbor); 0x130 -> value from lane+1 (right neighbor).
// bound_ctrl=false: boundary lanes keep their own value.
__device__ __forceinline__ float dpp_left(float x) {
    int r = __builtin_amdgcn_update_dpp(__float_as_int(x), __float_as_int(x),
                                        0x138, 0xF, 0xF, false);
    return __int_as_float(r);
}
__device__ __forceinline__ float dpp_right(float x) {
    int r = __builtin_amdgcn_update_dpp(__float_as_int(x), __float_as_int(x),
                                        0x130, 0xF, 0xF, false);
    return __int_as_float(r);
}

// One Gray-Scott step for a 4-px row segment, both fields, packed 2-wide in
// plain C (compiler-scheduled — R16 showed inline-asm VOP3P loses).
// Merged 5-point laplacian: DX2 == DY2 exactly on this grid (R14-validated).
__device__ __forceinline__ void row_step(
    f4 uN, f4 uC, f4 uD, float uL, float uR,
    f4 vN, f4 vC, f4 vD, float vL, float vR,
    float inv2, float Du, float Dv, float f, float fk, float dt,
    f4* outU, f4* outV)
{
    const f2 a0u = lo2(uC), a1u = hi2(uC);
    const f2 a0v = lo2(vC), a1v = hi2(vC);

    const f2 l0u = { uL, a0u.x };
    const f2 mmu = { a0u.y, a1u.x };
    const f2 r1u = { a1u.y, uR };
    const f2 l0v = { vL, a0v.x };
    const f2 mmv = { a0v.y, a1v.x };
    const f2 r1v = { a1v.y, vR };

    // lap = (left + right + up + down - 4*c) * inv2, clamped to [-10,10]
    const f2 lu0 = clamp2((l0u + mmu + (lo2(uN) + lo2(uD)) - 4.0f * a0u) * inv2,
                          -10.0f, 10.0f);
    const f2 lu1 = clamp2((mmu + r1u + (hi2(uN) + hi2(uD)) - 4.0f * a1u) * inv2,
                          -10.0f, 10.0f);
    const f2 lv0 = clamp2((l0v + mmv + (lo2(vN) + lo2(vD)) - 4.0f * a0v) * inv2,
                          -10.0f, 10.0f);
    const f2 lv1 = clamp2((mmv + r1v + (hi2(vN) + hi2(vD)) - 4.0f * a1v) * inv2,
                          -10.0f, 10.0f);

    const f2 uvv0 = a0u * a0v * a0v;
    const f2 uvv1 = a1u * a1v * a1v;

    const f2 du0 = clamp2(Du * lu0 - uvv0 + f * (1.0f - a0u), -1.0f, 1.0f);
    const f2 du1 = clamp2(Du * lu1 - uvv1 + f * (1.0f - a1u), -1.0f, 1.0f);
    const f2 dv0 = clamp2(Dv * lv0 + uvv0 - fk * a0v, -1.0f, 1.0f);
    const f2 dv1 = clamp2(Dv * lv1 + uvv1 - fk * a1v, -1.0f, 1.0f);

    const f2 ou0 = clamp2(a0u + du0 * dt, 0.0f, 2.0f);
    const f2 ou1 = clamp2(a1u + du1 * dt, 0.0f, 2.0f);
    const f2 ov0 = clamp2(a0v + dv0 * dt, 0.0f, 2.0f);
    const f2 ov1 = clamp2(a1v + dv1 * dt, 0.0f, 2.0f);

    *outU = __builtin_shufflevector(ou0, ou1, 0, 1, 2, 3);
    *outV = __builtin_shufflevector(ov0, ov1, 0, 1, 2, 3);
}

// 16 fused Gray-Scott steps on a 64x64 tile, halo 16 (R15 structure: DPP
// edges + sparse b32 fallbacks, fused step-16 global store). Step s computes
// rows/cols [s,95-s]; outside is clamped-finite garbage never read by the
// valid region.
__global__ __launch_bounds__(NTHREADS) void gs_tile(
    const float* __restrict__ Uin, const float* __restrict__ Vin,
    float* __restrict__ Uout, float* __restrict__ Vout,
    const float* __restrict__ pLogDu, const float* __restrict__ pLogDv,
    const float* __restrict__ pf, const float* __restrict__ pk,
    float inv2, float dt)
{
    __shared__ __align__(16) float sU[2][P * PITCHF];   // 2 x 38.4 KB
    __shared__ __align__(16) float sV[2][P * PITCHF];   // total 153.6 KB

    const int tid  = threadIdx.x;
    const int lane = tid & 63;
    const int bx = blockIdx.x & (NTX - 1);
    const int by = blockIdx.x >> 4;
    const int gx0 = bx * TILE - HALO;
    const int gy0 = by * TILE - HALO;

    const float Du = clampf(expf(pLogDu[0]), 0.001f, 1.0f);
    const float Dv = clampf(expf(pLogDv[0]), 0.001f, 1.0f);
    const float f = pf[0], k = pk[0];
    const float fk = f + k;

    // ---- load 96x96 halo'd tile (periodic wrap). No clamps: inputs are in
    // [0,2] by construction, so the reference's leading clip is the identity.
    for (int t = tid; t < P * (P / 4); t += NTHREADS) {   // 2304 4-px strips
        const int r  = t / (P / 4);
        const int c4 = (t - r * (P / 4)) * 4;
        const int gy = (gy0 + r) & (H - 1);
        const int gx = (gx0 + c4) & (W - 1);              // 4-aligned, no mid-vec wrap
        *reinterpret_cast<f4*>(&sU[0][r * PITCHF + c4]) = ld4f(Uin + gy * W + gx);
        *reinterpret_cast<f4*>(&sV[0][r * PITCHF + c4]) = ld4f(Vin + gy * W + gx);
    }
    __syncthreads();

    int b = 0;

#define GS_STEP(S, NC, C4LO)                                                     \
    {                                                                            \
        const float* __restrict__ cU = sU[b];                                    \
        const float* __restrict__ cV = sV[b];                                    \
        float* __restrict__ nU = sU[b ^ 1];                                      \
        float* __restrict__ nV = sV[b ^ 1];                                      \
        const int npair = (P - 2 * (S)) >> 1;                                    \
        const int tasks = npair * (NC);                                          \
        for (int t = tid; t < tasks; t += NTHREADS) {                            \
            const int pr  = t / (NC);                                            \
            const int j   = t - pr * (NC);                                       \
            const int row = (S) + 2 * pr;                                        \
            const int c4  = (C4LO) + j * 4;                                      \
            const int oA  = row * PITCHF + c4;                                   \
            const f4 uN = ld4f(cU + oA - PITCHF);                                \
            const f4 uA = ld4f(cU + oA);                                         \
            const f4 uB = ld4f(cU + oA + PITCHF);                                \
            const f4 uS = ld4f(cU + oA + 2 * PITCHF);                            \
            const f4 vN = ld4f(cV + oA - PITCHF);                                \
            const f4 vA = ld4f(cV + oA);                                         \
            const f4 vB = ld4f(cV + oA + PITCHF);                                \
            const f4 vS = ld4f(cV + oA + 2 * PITCHF);                            \
            float uLa = dpp_left(uA.w), uRa = dpp_right(uA.x);                   \
            float uLb = dpp_left(uB.w), uRb = dpp_right(uB.x);                   \
            float vLa = dpp_left(vA.w), vRa = dpp_right(vA.x);                   \
            float vLb = dpp_left(vB.w), vRb = dpp_right(vB.x);                   \
            if ((lane == 0 || j == 0) && c4 > 0) {                               \
                uLa = cU[oA - 1]; uLb = cU[oA + PITCHF - 1];                     \
                vLa = cV[oA - 1]; vLb = cV[oA + PITCHF - 1];                     \
            }                                                                    \
            if (lane == 63 || j == (NC) - 1) {                                   \
                uRa = cU[oA + 4]; uRb = cU[oA + PITCHF + 4];                     \
                vRa = cV[oA + 4]; vRb = cV[oA + PITCHF + 4];                     \
            }                                                                    \
            f4 ouA, ovA, ouB, ovB;                                               \
            row_step(uN, uA, uB, uLa, uRa, vN, vA, vB, vLa, vRa,                 \
                     inv2, Du, Dv, f, fk, dt, &ouA, &ovA);                       \
            row_step(uA, uB, uS, uLb, uRb, vA, vB, vS, vLb, vRb,                 \
                     inv2, Du, Dv, f, fk, dt, &ouB, &ovB);                       \
            *reinterpret_cast<f4*>(nU + oA)          = ouA;                      \
            *reinterpret_cast<f4*>(nU + oA + PITCHF) = ouB;                      \
            *reinterpret_cast<f4*>(nV + oA)          = ovA;                      \
            *reinterpret_cast<f4*>(nV + oA + PITCHF) = ovB;                      \
        }                                                                        \
        b ^= 1;                                                                  \
        __syncthreads();                                                         \
    }

    for (int s = 1; s <= 3; ++s)   GS_STEP(s, 24,  0);    // s=1..3
    for (int s = 4; s <= 7; ++s)   GS_STEP(s, 22,  4);    // s=4..7
    for (int s = 8; s <= 11; ++s)  GS_STEP(s, 20,  8);    // s=8..11
    for (int s = 12; s <= 15; ++s) GS_STEP(s, 18, 12);    // s=12..15

    // ---- step 16: region is exactly the interior [16,79]^2 -> write global.
    // NC=16 divides 64: j==0 covers lane 0, j==15 covers lane 63.
    {
        const float* __restrict__ cU = sU[b];
        const float* __restrict__ cV = sV[b];
        if (tid < 32 * 16) {                              // 512 tasks
            const int pr  = tid / 16;
            const int j   = tid - pr * 16;
            const int row = 16 + 2 * pr;
            const int c4  = 16 + j * 4;
            const int oA  = row * PITCHF + c4;
            const f4 uN = ld4f(cU + oA - PITCHF);
            const f4 uA = ld4f(cU + oA);
            const f4 uB = ld4f(cU + oA + PITCHF);
            const f4 uS = ld4f(cU + oA + 2 * PITCHF);
            const f4 vN = ld4f(cV + oA - PITCHF);
            const f4 vA = ld4f(cV + oA);
            const f4 vB = ld4f(cV + oA + PITCHF);
            const f4 vS = ld4f(cV + oA + 2 * PITCHF);
            float uLa = dpp_left(uA.w), uRa = dpp_right(uA.x);
            float uLb = dpp_left(uB.w), uRb = dpp_right(uB.x);
            float vLa = dpp_left(vA.w), vRa = dpp_right(vA.x);
            float vLb = dpp_left(vB.w), vRb = dpp_right(vB.x);
            if (j == 0) {
                uLa = cU[oA - 1]; uLb = cU[oA + PITCHF - 1];
                vLa = cV[oA - 1]; vLb = cV[oA + PITCHF - 1];
            }
            if (j == 15) {
                uRa = cU[oA + 4]; uRb = cU[oA + PITCHF + 4];
                vRa = cV[oA + 4]; vRb = cV[oA + PITCHF + 4];
            }
            f4 ouA, ovA, ouB, ovB;
            row_step(uN, uA, uB, uLa, uRa, vN, vA, vB, vLa, vRa,
                     inv2, Du, Dv, f, fk, dt, &ouA, &ovA);
            row_step(uA, uB, uS, uLb, uRb, vA, vB, vS, vLb, vRb,
                     inv2, Du, Dv, f, fk, dt, &ouB, &ovB);
            const int go = (by * TILE + row - HALO) * W + bx * TILE + (c4 - HALO);
            *reinterpret_cast<f4*>(Uout + go)     = ouA;
            *reinterpret_cast<f4*>(Uout + go + W) = ouB;
            *reinterpret_cast<f4*>(Vout + go)     = ovA;
            *reinterpret_cast<f4*>(Vout + go + W) = ovB;
        }
    }
#undef GS_STEP
}

} // namespace

extern "C" void kernel_launch(void* const* d_in, const int* in_sizes, int n_in,
                              void* d_out, int out_size, void* d_ws, size_t ws_size,
                              hipStream_t stream) {
    const float* U0     = (const float*)d_in[0];
    const float* V0     = (const float*)d_in[1];
    const float* pLogDu = (const float*)d_in[2];
    const float* pLogDv = (const float*)d_in[3];
    const float* pf     = (const float*)d_in[4];
    const float* pk     = (const float*)d_in[5];
    // d_in[6] = steps (int32) — fixed at 64 by the problem definition.

    float* wsU  = (float*)d_ws;   // 4 MB
    float* wsV  = wsU + HW;       // 4 MB
    float* outU = (float*)d_out;  // output layout: [U (HW) | V (HW)]
    float* outV = outU + HW;

    const double dx  = 1.0 / (W - 1);
    const double dx2 = dx * dx;                 // == dy2 exactly (square grid)
    const float inv2 = (float)(1.0 / dx2);
    const float dtf  = (float)(0.1 * dx2 / (4.0 * 0.16));

    const int grid = (H / TILE) * (W / TILE);   // 256 blocks = 1 per CU

    // 4 launches of 16 fused steps, ping-pong ws <-> d_out; launch 3 (odd)
    // leaves the final state exactly in d_out.
    const float* cu = U0;
    const float* cv = V0;
    for (int l = 0; l < NLAUNCH; ++l) {
        float* nu;
        float* nv;
        if (l & 1) { nu = outU; nv = outV; }
        else       { nu = wsU;  nv = wsV;  }
        gs_tile<<<grid, NTHREADS, 0, stream>>>(cu, cv, nu, nv,
                                               pLogDu, pLogDv, pf, pk,
                                               inv2, dtf);
        cu = nu; cv = nv;
    }
}